// Round 8
// baseline (160.621 us; speedup 1.0000x reference)
//
#include <hip/hip_runtime.h>
#include <cstdint>
#include <cstddef>

#define DIMC    192
#define NHEADS  6
#define NATT    486
#define NB      16
#define NH      56
#define NWW     56
#define HPOOL   28
#define WPOOL   28
#define NPIX    784
#define VH      58
#define VW      58
#define MROWS   (NB*NH*NWW)      // 50176
#define MPOOL   (NB*NPIX)        // 12544
#define SCALE_A 0.17677669529663687f

using bf16x8 = __attribute__((ext_vector_type(8))) short;
using f32x4  = __attribute__((ext_vector_type(4))) float;
typedef unsigned int u32x4a __attribute__((vector_size(16), aligned(4)));

static __device__ __forceinline__ unsigned short f2bf(float f) {
    unsigned int u = __float_as_uint(f);
    unsigned int r = (u + 0x7fffu + ((u >> 16) & 1u)) >> 16;   // RNE
    return (unsigned short)r;
}
static __device__ __forceinline__ float bf2f(unsigned short u) {
    return __uint_as_float((unsigned int)u << 16);
}

// =====================================================================
// Weight prep: WTv/WTp[n][k] = bf16(W[k][n]); WaT[512][192] = bf16(Wa[k][n]*SCALE)
// =====================================================================
__global__ __launch_bounds__(256)
void wt_convert_kernel(const float* __restrict__ Wv, const float* __restrict__ Wp,
                       const float* __restrict__ Wa,
                       unsigned short* __restrict__ WTv, unsigned short* __restrict__ WTp,
                       unsigned short* __restrict__ WaT)
{
    int idx = blockIdx.x * 256 + threadIdx.x;        // 0..172031
    if (idx < 73728) {
        int sel = idx / 36864;
        int r   = idx - sel * 36864;
        int n   = r / DIMC;
        int k   = r - n * DIMC;
        const float* W = sel ? Wp : Wv;
        unsigned short* WT = sel ? WTp : WTv;
        WT[r] = f2bf(W[k * DIMC + n]);
    } else {
        int r = idx - 73728;                          // 0..98303
        int n = r / DIMC;
        int k = r - n * DIMC;
        WaT[r] = (n < NATT) ? f2bf(Wa[(size_t)k * NATT + n] * SCALE_A) : (unsigned short)0;
    }
}

// =====================================================================
// Zero the 1-pixel border of vp (bf16), as uint writes
// =====================================================================
__global__ __launch_bounds__(256)
void vp_border_zero_kernel(unsigned int* __restrict__ vpu)
{
    int idx = blockIdx.x * 256 + threadIdx.x;
    if (idx >= 350208) return;
    int cu   = idx % 96;
    int rest = idx / 96;
    int b    = rest / 228;
    int p    = rest - b * 228;
    int hi, wi;
    if (p < 58)       { hi = 0;  wi = p; }
    else if (p < 116) { hi = 57; wi = p - 58; }
    else { int q = p - 116; hi = 1 + (q >> 1); wi = (q & 1) * 57; }
    vpu[(((size_t)b * VH + hi) * VW + wi) * 96 + cu] = 0u;
}

// =====================================================================
// MFMA GEMM, BM=64, BN=192 (full), 4 waves (2x2). (R5-proven form)
// MODE 0: A fp32 (x), C bf16 scattered into padded vp
// MODE 1: A bf16 (y), C fp32 + bias -> out
// =====================================================================
template<int MODE>
__global__ __launch_bounds__(256)
void mfma_gemm_kernel(const void* __restrict__ Av, const unsigned short* __restrict__ WT,
                      const float* __restrict__ bias, void* __restrict__ Cv)
{
    __shared__ unsigned short As[64 * DIMC];   // 24 KB swizzled bf16

    const int t  = threadIdx.x;
    const int l  = t & 63;
    const int w  = t >> 6;
    const int wr = w >> 1;
    const int wc = w & 1;
    const int by = blockIdx.x;

    if (MODE == 0) {
        const float* Ab = (const float*)Av + (size_t)by * 64 * DIMC;
#pragma unroll
        for (int i = 0; i < 12; ++i) {
            int f = i * 1024 + t * 4;
            float4 v = *(const float4*)(Ab + f);
            int row = f / DIMC;
            int k   = f - row * DIMC;
            ushort4 u;
            u.x = f2bf(v.x); u.y = f2bf(v.y); u.z = f2bf(v.z); u.w = f2bf(v.w);
            int off = (row * 384 + k * 2) ^ ((row & 7) << 4);
            *(ushort4*)((char*)As + off) = u;
        }
    } else {
        const unsigned short* Ab = (const unsigned short*)Av + (size_t)by * 64 * DIMC;
#pragma unroll
        for (int i = 0; i < 6; ++i) {
            int f = i * 2048 + t * 8;
            bf16x8 v = *(const bf16x8*)(Ab + f);
            int row = f / DIMC;
            int k   = f - row * DIMC;
            int off = (row * 384 + k * 2) ^ ((row & 7) << 4);
            *(bf16x8*)((char*)As + off) = v;
        }
    }
    __syncthreads();

    f32x4 acc[2][6];
#pragma unroll
    for (int mi = 0; mi < 2; ++mi)
#pragma unroll
        for (int ni = 0; ni < 6; ++ni) acc[mi][ni] = (f32x4)0.f;

    const int arow0 = wr * 32 + (l & 15);
    const int kb    = (l >> 4) << 4;

#pragma unroll
    for (int ks = 0; ks < 6; ++ks) {
        bf16x8 a[2], b[6];
#pragma unroll
        for (int mi = 0; mi < 2; ++mi) {
            int row = arow0 + mi * 16;
            int off = (row * 384 + ks * 64 + kb) ^ ((row & 7) << 4);
            a[mi] = *(const bf16x8*)((const char*)As + off);
        }
#pragma unroll
        for (int ni = 0; ni < 6; ++ni) {
            int n = wc * 96 + ni * 16 + (l & 15);
            b[ni] = *(const bf16x8*)(WT + (size_t)n * DIMC + ks * 32 + ((l >> 4) << 3));
        }
#pragma unroll
        for (int mi = 0; mi < 2; ++mi)
#pragma unroll
            for (int ni = 0; ni < 6; ++ni)
                acc[mi][ni] = __builtin_amdgcn_mfma_f32_16x16x32_bf16(
                    a[mi], b[ni], acc[mi][ni], 0, 0, 0);
    }

#pragma unroll
    for (int mi = 0; mi < 2; ++mi) {
#pragma unroll
        for (int r = 0; r < 4; ++r) {
            int m = by * 64 + wr * 32 + mi * 16 + ((l >> 4) << 2) + r;
            if (MODE == 1) {
                float* dst = (float*)Cv + (size_t)m * DIMC;
#pragma unroll
                for (int ni = 0; ni < 6; ++ni) {
                    int col = wc * 96 + ni * 16 + (l & 15);
                    dst[col] = acc[mi][ni][r] + bias[col];
                }
            } else {
                int bb = m / (NH * NWW);
                int rr = m - bb * (NH * NWW);
                int hi = rr / NWW;
                int wi = rr - hi * NWW;
                unsigned short* dst = (unsigned short*)Cv +
                    (((size_t)bb * VH + hi + 1) * VW + (wi + 1)) * DIMC;
#pragma unroll
                for (int ni = 0; ni < 6; ++ni) {
                    int col = wc * 96 + ni * 16 + (l & 15);
                    dst[col] = f2bf(acc[mi][ni][r]);
                }
            }
        }
    }
}

// =====================================================================
// Fused pool + MFMA GEMM (M=12544, N=512pad, K=192) + softmax -> attn bf16
// =====================================================================
__global__ __launch_bounds__(512)
void pool_attn_mfma_kernel(const float* __restrict__ x, const unsigned short* __restrict__ WaT,
                           const float* __restrict__ ba, unsigned short* __restrict__ attn)
{
    __shared__ unsigned short As[64 * DIMC];   // 24 KB
    __shared__ float Cs[16][489];              // 31.3 KB chunk
    __shared__ float ba_s[NATT];

    const int t  = threadIdx.x;
    const int l  = t & 63;
    const int w  = t >> 6;
    const int wr = w >> 2;
    const int wc = w & 3;
    const int by = blockIdx.x;

    if (t < NATT) ba_s[t] = ba[t] * SCALE_A;

#pragma unroll
    for (int i = 0; i < 6; ++i) {
        int f   = i * 2048 + t * 4;
        int row = f / DIMC;
        int k   = f - row * DIMC;
        int m   = by * 64 + row;
        int b   = m / NPIX;
        int r   = m - b * NPIX;
        int hh  = r / WPOOL;
        int ww  = r - hh * WPOOL;
        const float* xp = x + (((size_t)(b * NH + hh * 2)) * NWW + ww * 2) * DIMC + k;
        float4 v0 = *(const float4*)(xp);
        float4 v1 = *(const float4*)(xp + DIMC);
        float4 v2 = *(const float4*)(xp + (size_t)NWW * DIMC);
        float4 v3 = *(const float4*)(xp + (size_t)NWW * DIMC + DIMC);
        ushort4 u;
        u.x = f2bf(0.25f * (v0.x + v1.x + v2.x + v3.x));
        u.y = f2bf(0.25f * (v0.y + v1.y + v2.y + v3.y));
        u.z = f2bf(0.25f * (v0.z + v1.z + v2.z + v3.z));
        u.w = f2bf(0.25f * (v0.w + v1.w + v2.w + v3.w));
        int off = (row * 384 + k * 2) ^ ((row & 7) << 4);
        *(ushort4*)((char*)As + off) = u;
    }
    __syncthreads();

    f32x4 acc[2][8];
#pragma unroll
    for (int mi = 0; mi < 2; ++mi)
#pragma unroll
        for (int ni = 0; ni < 8; ++ni) acc[mi][ni] = (f32x4)0.f;

    const int arow0 = wr * 32 + (l & 15);
    const int kb    = (l >> 4) << 4;

#pragma unroll
    for (int ks = 0; ks < 6; ++ks) {
        bf16x8 a[2], b[8];
#pragma unroll
        for (int mi = 0; mi < 2; ++mi) {
            int row = arow0 + mi * 16;
            int off = (row * 384 + ks * 64 + kb) ^ ((row & 7) << 4);
            a[mi] = *(const bf16x8*)((const char*)As + off);
        }
#pragma unroll
        for (int ni = 0; ni < 8; ++ni) {
            int n = wc * 128 + ni * 16 + (l & 15);
            b[ni] = *(const bf16x8*)(WaT + (size_t)n * DIMC + ks * 32 + ((l >> 4) << 3));
        }
#pragma unroll
        for (int mi = 0; mi < 2; ++mi)
#pragma unroll
            for (int ni = 0; ni < 8; ++ni)
                acc[mi][ni] = __builtin_amdgcn_mfma_f32_16x16x32_bf16(
                    a[mi], b[ni], acc[mi][ni], 0, 0, 0);
    }

#pragma unroll
    for (int r0 = 0; r0 < 64; r0 += 16) {
        const int mi = (r0 >> 4) & 1;
        if (wr == (r0 >> 5)) {
#pragma unroll
            for (int ni = 0; ni < 8; ++ni) {
                int col = wc * 128 + ni * 16 + (l & 15);
                if (col < NATT) {
#pragma unroll
                    for (int r = 0; r < 4; ++r)
                        Cs[((l >> 4) << 2) + r][col] =
                            (mi == 0 ? acc[0][ni][r] : acc[1][ni][r]) + ba_s[col];
                }
            }
        }
        __syncthreads();
        for (int g = t; g < 864; g += 512) {
            int lr = g / 54;
            int gc = (g - lr * 54) * 9;
            const float* ap = &Cs[lr][gc];
            float mx = ap[0];
#pragma unroll
            for (int q = 1; q < 9; ++q) mx = fmaxf(mx, ap[q]);
            float e[9];
            float sum = 0.f;
#pragma unroll
            for (int q = 0; q < 9; ++q) { e[q] = __expf(ap[q] - mx); sum += e[q]; }
            float inv = 1.f / sum;
            int m = by * 64 + r0 + lr;
            unsigned short* dst = attn + (size_t)m * NATT + gc;
#pragma unroll
            for (int q = 0; q < 9; ++q) dst[q] = f2bf(e[q] * inv);
        }
        __syncthreads();
    }
}

// =====================================================================
// LDS-tiled gather. Block = 4(p) x 8(q) pixel tile of one batch.
// Stage vp region [7 rows][11 cols][192 ch] -> vpS[7][11][200] (bank pad)
// and attn windows [3][5][486] -> atS[15][488]. Compute from LDS.
// Wave = parity class -> all branches wave-uniform. Lane = pixel x 8ch.
// =====================================================================
template<int NI, int NJ>
static __device__ __forceinline__ void gbody(
    int b, int p, int q, int pp, int qq, int cg0,
    const unsigned short* vpS, const unsigned short* atS,
    unsigned short* __restrict__ y)
{
    const int pr  = p >> 1, qr = q >> 1;
    const int prL = pp >> 1, qrL = qq >> 1;

    float acc[3][8];
#pragma unroll
    for (int j = 0; j < 3; ++j)
#pragma unroll
        for (int e = 0; e < 8; ++e) acc[j][e] = 0.f;

#pragma unroll
    for (int wi = 0; wi < NI; ++wi) {
        const bool hv  = (NI == 1) || (wi == 0) || (pr + 1 < HPOOL);
        const int  iof = (NI == 1) ? 1 : (wi ? 0 : 2);
        const int  wiL = prL + wi;
#pragma unroll
        for (int wj = 0; wj < NJ; ++wj) {
            const bool wv  = (NJ == 1) || (wj == 0) || (qr + 1 < WPOOL);
            const int  jof = (NJ == 1) ? 1 : (wj ? 0 : 2);
            const int  wjL = qrL + wj;
            const bool ok  = hv && wv;

            const unsigned short* win = &atS[(wiL * 5 + wjL) * 488 + (iof * 3 + jof) * 9];
            const unsigned short* vb  = &vpS[(2 * wiL) * 2200 + (2 * wjL) * 200];

#pragma unroll
            for (int j = 0; j < 3; ++j) {
                const int head = 2 * j + (cg0 >> 2);
                float a_[9];
#pragma unroll
                for (int k = 0; k < 9; ++k)
                    a_[k] = ok ? bf2f(win[head * 81 + k]) : 0.f;
                const int ch0 = 64 * j + 8 * cg0;
#pragma unroll
                for (int qi = 0; qi < 3; ++qi)
#pragma unroll
                    for (int qj = 0; qj < 3; ++qj) {
                        bf16x8 v = *(const bf16x8*)&vb[qi * 2200 + qj * 200 + ch0];
                        float aw = a_[qi * 3 + qj];
#pragma unroll
                        for (int e = 0; e < 8; ++e)
                            acc[j][e] = fmaf(aw, bf2f((unsigned short)v[e]), acc[j][e]);
                    }
            }
        }
    }

    size_t pix = ((size_t)b * NH + p) * NWW + q;
#pragma unroll
    for (int j = 0; j < 3; ++j) {
        bf16x8 r;
#pragma unroll
        for (int e = 0; e < 8; ++e) r[e] = (short)f2bf(acc[j][e]);
        *(bf16x8*)(y + pix * DIMC + 64 * j + 8 * cg0) = r;
    }
}

__global__ __launch_bounds__(256)
void gather_tiled_kernel(const unsigned short* __restrict__ attn,
                         const unsigned short* __restrict__ vp,
                         unsigned short* __restrict__ y)
{
    __shared__ unsigned short vpS[7 * 11 * 200];   // 30.8 KB
    __shared__ unsigned short atS[15 * 488];       // 14.6 KB

    const int t = threadIdx.x;
    // bijective XCD swizzle: 1568 = 8*196; XCD i owns batches 2i,2i+1
    const int flat = blockIdx.x;
    const int wg   = (flat & 7) * 196 + (flat >> 3);
    const int b    = wg / 98;
    const int tile = wg - b * 98;          // 14*7
    const int tr   = tile / 7;             // 0..13
    const int tc   = tile - tr * 7;        // 0..6
    const int p0 = tr * 4, q0 = tc * 8;
    const int hh0 = tr * 2, ww0 = tc * 4;

    // ---- stage vp region: rows p0..p0+6 (clamped), cols q0..q0+10, all ch ----
#pragma unroll
    for (int it = 0; it < 8; ++it) {
        int idx = it * 256 + t;                    // 1848 chunks of 8 elems
        if (idx < 1848) {
            int r  = idx / 264;
            int e8 = idx - r * 264;                // 0..263 -> elem e8*8 in [0,2112)
            int gr = p0 + r; if (gr > VH - 1) gr = VH - 1;
            const unsigned short* src = vp + (((size_t)b * VH + gr) * VW + q0) * DIMC + e8 * 8;
            bf16x8 v = *(const bf16x8*)src;        // 16B aligned
            int cc = e8 / 24;
            int ch = (e8 - cc * 24) * 8;
            *(bf16x8*)&vpS[r * 2200 + cc * 200 + ch] = v;
        }
    }
    // ---- stage attn windows: hh0..hh0+2 x ww0..ww0+4 (clamped), 61 x 16B per window ----
#pragma unroll
    for (int it = 0; it < 4; ++it) {
        int idx = it * 256 + t;                    // 915 chunks
        if (idx < 915) {
            int win = idx / 61;
            int c   = idx - win * 61;
            int wi = win / 5, wj = win - wi * 5;
            int hh = hh0 + wi; if (hh > HPOOL - 1) hh = HPOOL - 1;
            int ww = ww0 + wj; if (ww > WPOOL - 1) ww = WPOOL - 1;
            const u32x4a* src = (const u32x4a*)(attn +
                (size_t)(b * NPIX + hh * WPOOL + ww) * NATT + c * 8);   // 4B-aligned
            u32x4a v = *src;
            *(u32x4a*)&atS[win * 488 + c * 8] = v;
        }
    }
    __syncthreads();

    const int w   = t >> 6, l = t & 63;
    const int px  = l >> 3;                // 8 pixels per wave
    const int cg0 = l & 7;                 // 8 channel-groups (8 ch each)
    const int pcl = w >> 1, qcl = w & 1;   // wave parity class
    const int pp  = ((px >> 2) << 1) | pcl;   // {pcl, 2+pcl}
    const int qq  = ((px & 3) << 1) | qcl;    // {qcl, 2+qcl, 4+qcl, 6+qcl}
    const int p   = p0 + pp, q = q0 + qq;

    if      (w == 0) gbody<1, 1>(b, p, q, pp, qq, cg0, vpS, atS, y);
    else if (w == 1) gbody<1, 2>(b, p, q, pp, qq, cg0, vpS, atS, y);
    else if (w == 2) gbody<2, 1>(b, p, q, pp, qq, cg0, vpS, atS, y);
    else             gbody<2, 2>(b, p, q, pp, qq, cg0, vpS, atS, y);
}

// =====================================================================
extern "C" void kernel_launch(void* const* d_in, const int* in_sizes, int n_in,
                              void* d_out, int out_size, void* d_ws, size_t ws_size,
                              hipStream_t stream)
{
    const float* x  = (const float*)d_in[0];
    const float* Wv = (const float*)d_in[1];
    const float* Wa = (const float*)d_in[2];
    const float* ba = (const float*)d_in[3];
    const float* Wp = (const float*)d_in[4];
    const float* bp = (const float*)d_in[5];
    float* out = (float*)d_out;

    const size_t vp_elems   = (size_t)NB * VH * VW * DIMC;   // bf16
    const size_t attn_elems = (size_t)MPOOL * NATT;          // bf16
    const size_t y_elems    = (size_t)MROWS * DIMC;          // bf16

    unsigned short* vp   = (unsigned short*)d_ws;
    unsigned short* attn = vp + vp_elems;
    unsigned short* y    = attn + attn_elems;
    unsigned short* WTv  = y + y_elems;
    unsigned short* WTp  = WTv + 36864;
    unsigned short* WaT  = WTp + 36864;

    vp_border_zero_kernel<<<1369, 256, 0, stream>>>((unsigned int*)vp);
    wt_convert_kernel<<<672, 256, 0, stream>>>(Wv, Wp, Wa, WTv, WTp, WaT);

    mfma_gemm_kernel<0><<<MROWS / 64, 256, 0, stream>>>(x, WTv, nullptr, vp);
    pool_attn_mfma_kernel<<<MPOOL / 64, 512, 0, stream>>>(x, WaT, ba, attn);

    gather_tiled_kernel<<<1568, 256, 0, stream>>>(attn, vp, y);

    mfma_gemm_kernel<1><<<MROWS / 64, 256, 0, stream>>>(y, WTp, bp, out);
}

// Round 9
// 122.691 us; speedup vs baseline: 1.3092x; 1.3092x over previous
//
#include <hip/hip_runtime.h>
#include <cstdint>
#include <cstddef>

#define DIMC    192
#define NHEADS  6
#define NATT    486
#define NB      16
#define NH      56
#define NWW     56
#define HPOOL   28
#define WPOOL   28
#define NPIX    784
#define VH      58
#define VW      58
#define MROWS   (NB*NH*NWW)      // 50176
#define MPOOL   (NB*NPIX)        // 12544
#define SCALE_A 0.17677669529663687f

using bf16x8 = __attribute__((ext_vector_type(8))) short;
using f32x4  = __attribute__((ext_vector_type(4))) float;

static __device__ __forceinline__ unsigned short f2bf(float f) {
    unsigned int u = __float_as_uint(f);
    unsigned int r = (u + 0x7fffu + ((u >> 16) & 1u)) >> 16;   // RNE
    return (unsigned short)r;
}
static __device__ __forceinline__ float bf2f(unsigned short u) {
    return __uint_as_float((unsigned int)u << 16);
}

// =====================================================================
// Weight prep: WTv/WTp[n][k] = bf16(W[k][n]); WaT[512][192] = bf16(Wa[k][n]*SCALE)
// =====================================================================
__global__ __launch_bounds__(256)
void wt_convert_kernel(const float* __restrict__ Wv, const float* __restrict__ Wp,
                       const float* __restrict__ Wa,
                       unsigned short* __restrict__ WTv, unsigned short* __restrict__ WTp,
                       unsigned short* __restrict__ WaT)
{
    int idx = blockIdx.x * 256 + threadIdx.x;        // 0..172031
    if (idx < 73728) {
        int sel = idx / 36864;
        int r   = idx - sel * 36864;
        int n   = r / DIMC;
        int k   = r - n * DIMC;
        const float* W = sel ? Wp : Wv;
        unsigned short* WT = sel ? WTp : WTv;
        WT[r] = f2bf(W[k * DIMC + n]);
    } else {
        int r = idx - 73728;                          // 0..98303
        int n = r / DIMC;
        int k = r - n * DIMC;
        WaT[r] = (n < NATT) ? f2bf(Wa[(size_t)k * NATT + n] * SCALE_A) : (unsigned short)0;
    }
}

// =====================================================================
// Zero the 1-pixel border of vp (bf16), as uint writes
// =====================================================================
__global__ __launch_bounds__(256)
void vp_border_zero_kernel(unsigned int* __restrict__ vpu)
{
    int idx = blockIdx.x * 256 + threadIdx.x;
    if (idx >= 350208) return;
    int cu   = idx % 96;
    int rest = idx / 96;
    int b    = rest / 228;
    int p    = rest - b * 228;
    int hi, wi;
    if (p < 58)       { hi = 0;  wi = p; }
    else if (p < 116) { hi = 57; wi = p - 58; }
    else { int q = p - 116; hi = 1 + (q >> 1); wi = (q & 1) * 57; }
    vpu[(((size_t)b * VH + hi) * VW + wi) * 96 + cu] = 0u;
}

// =====================================================================
// MFMA GEMM, BM=64, BN=192 (full), 4 waves (2x2).
// MODE 0: A fp32 (x), C bf16 -> padded vp   (LDS-staged coalesced stores)
// MODE 1: A bf16 (y), C fp32 + bias -> out  (LDS-staged coalesced stores)
// =====================================================================
template<int MODE>
__global__ __launch_bounds__(256)
void mfma_gemm_kernel(const void* __restrict__ Av, const unsigned short* __restrict__ WT,
                      const float* __restrict__ bias, void* __restrict__ Cv)
{
    __shared__ unsigned short As[64 * DIMC];   // 24 KB swizzled bf16 (reused in epilogue)

    const int t  = threadIdx.x;
    const int l  = t & 63;
    const int w  = t >> 6;
    const int wr = w >> 1;
    const int wc = w & 1;
    const int by = blockIdx.x;

    if (MODE == 0) {
        const float* Ab = (const float*)Av + (size_t)by * 64 * DIMC;
#pragma unroll
        for (int i = 0; i < 12; ++i) {
            int f = i * 1024 + t * 4;
            float4 v = *(const float4*)(Ab + f);
            int row = f / DIMC;
            int k   = f - row * DIMC;
            ushort4 u;
            u.x = f2bf(v.x); u.y = f2bf(v.y); u.z = f2bf(v.z); u.w = f2bf(v.w);
            int off = (row * 384 + k * 2) ^ ((row & 7) << 4);
            *(ushort4*)((char*)As + off) = u;
        }
    } else {
        const unsigned short* Ab = (const unsigned short*)Av + (size_t)by * 64 * DIMC;
#pragma unroll
        for (int i = 0; i < 6; ++i) {
            int f = i * 2048 + t * 8;
            bf16x8 v = *(const bf16x8*)(Ab + f);
            int row = f / DIMC;
            int k   = f - row * DIMC;
            int off = (row * 384 + k * 2) ^ ((row & 7) << 4);
            *(bf16x8*)((char*)As + off) = v;
        }
    }
    __syncthreads();

    f32x4 acc[2][6];
#pragma unroll
    for (int mi = 0; mi < 2; ++mi)
#pragma unroll
        for (int ni = 0; ni < 6; ++ni) acc[mi][ni] = (f32x4)0.f;

    const int arow0 = wr * 32 + (l & 15);
    const int kb    = (l >> 4) << 4;

#pragma unroll
    for (int ks = 0; ks < 6; ++ks) {
        bf16x8 a[2], b[6];
#pragma unroll
        for (int mi = 0; mi < 2; ++mi) {
            int row = arow0 + mi * 16;
            int off = (row * 384 + ks * 64 + kb) ^ ((row & 7) << 4);
            a[mi] = *(const bf16x8*)((const char*)As + off);
        }
#pragma unroll
        for (int ni = 0; ni < 6; ++ni) {
            int n = wc * 96 + ni * 16 + (l & 15);
            b[ni] = *(const bf16x8*)(WT + (size_t)n * DIMC + ks * 32 + ((l >> 4) << 3));
        }
#pragma unroll
        for (int mi = 0; mi < 2; ++mi)
#pragma unroll
            for (int ni = 0; ni < 6; ++ni)
                acc[mi][ni] = __builtin_amdgcn_mfma_f32_16x16x32_bf16(
                    a[mi], b[ni], acc[mi][ni], 0, 0, 0);
    }

    if (MODE == 0) {
        // stage bf16 C tile in LDS (linear), then coalesced 16B row stores
        __syncthreads();
#pragma unroll
        for (int mi = 0; mi < 2; ++mi) {
#pragma unroll
            for (int r = 0; r < 4; ++r) {
                int row = wr * 32 + mi * 16 + ((l >> 4) << 2) + r;
#pragma unroll
                for (int ni = 0; ni < 6; ++ni) {
                    int col = wc * 96 + ni * 16 + (l & 15);
                    As[row * DIMC + col] = f2bf(acc[mi][ni][r]);
                }
            }
        }
        __syncthreads();
#pragma unroll
        for (int i = 0; i < 6; ++i) {
            int f   = i * 2048 + t * 8;       // ushort idx
            int row = f / DIMC;
            int k   = f - row * DIMC;
            int m   = by * 64 + row;
            int bb  = m / (NH * NWW);
            int rr  = m - bb * (NH * NWW);
            int hi  = rr / NWW;
            int wi  = rr - hi * NWW;
            bf16x8 v = *(const bf16x8*)&As[f];
            unsigned short* dst = (unsigned short*)Cv +
                (((size_t)bb * VH + hi + 1) * VW + (wi + 1)) * DIMC + k;
            *(bf16x8*)dst = v;
        }
    } else {
        // stage fp32 C tile in LDS in two 32-row chunks, coalesced float4 stores
        float* fAs = (float*)As;              // 6144 floats = 32 rows
#pragma unroll
        for (int chunk = 0; chunk < 2; ++chunk) {
            __syncthreads();
            if (wr == chunk) {
#pragma unroll
                for (int mi = 0; mi < 2; ++mi) {
#pragma unroll
                    for (int r = 0; r < 4; ++r) {
                        int rowl = mi * 16 + ((l >> 4) << 2) + r;
#pragma unroll
                        for (int ni = 0; ni < 6; ++ni) {
                            int col = wc * 96 + ni * 16 + (l & 15);
                            fAs[rowl * DIMC + col] = acc[mi][ni][r];
                        }
                    }
                }
            }
            __syncthreads();
#pragma unroll
            for (int i = 0; i < 6; ++i) {
                int f   = i * 1024 + t * 4;   // float idx
                int row = f / DIMC;
                int k   = f - row * DIMC;
                int m   = by * 64 + chunk * 32 + row;
                float4 v  = *(const float4*)&fAs[f];
                float4 bv = *(const float4*)&bias[k];
                v.x += bv.x; v.y += bv.y; v.z += bv.z; v.w += bv.w;
                *(float4*)((float*)Cv + (size_t)m * DIMC + k) = v;
            }
        }
    }
}

// =====================================================================
// Fused pool + MFMA GEMM (M=12544, N=512pad, K=192) + softmax
// -> attn_pad bf16, layout [m][54][16] (9 weights + 7 pad per row)
// =====================================================================
__global__ __launch_bounds__(512)
void pool_attn_mfma_kernel(const float* __restrict__ x, const unsigned short* __restrict__ WaT,
                           const float* __restrict__ ba, unsigned short* __restrict__ attn)
{
    __shared__ unsigned short As[64 * DIMC];   // 24 KB
    __shared__ float Cs[16][489];              // 31.3 KB chunk
    __shared__ float ba_s[NATT];

    const int t  = threadIdx.x;
    const int l  = t & 63;
    const int w  = t >> 6;
    const int wr = w >> 2;
    const int wc = w & 3;
    const int by = blockIdx.x;

    if (t < NATT) ba_s[t] = ba[t] * SCALE_A;

#pragma unroll
    for (int i = 0; i < 6; ++i) {
        int f   = i * 2048 + t * 4;
        int row = f / DIMC;
        int k   = f - row * DIMC;
        int m   = by * 64 + row;
        int b   = m / NPIX;
        int r   = m - b * NPIX;
        int hh  = r / WPOOL;
        int ww  = r - hh * WPOOL;
        const float* xp = x + (((size_t)(b * NH + hh * 2)) * NWW + ww * 2) * DIMC + k;
        float4 v0 = *(const float4*)(xp);
        float4 v1 = *(const float4*)(xp + DIMC);
        float4 v2 = *(const float4*)(xp + (size_t)NWW * DIMC);
        float4 v3 = *(const float4*)(xp + (size_t)NWW * DIMC + DIMC);
        ushort4 u;
        u.x = f2bf(0.25f * (v0.x + v1.x + v2.x + v3.x));
        u.y = f2bf(0.25f * (v0.y + v1.y + v2.y + v3.y));
        u.z = f2bf(0.25f * (v0.z + v1.z + v2.z + v3.z));
        u.w = f2bf(0.25f * (v0.w + v1.w + v2.w + v3.w));
        int off = (row * 384 + k * 2) ^ ((row & 7) << 4);
        *(ushort4*)((char*)As + off) = u;
    }
    __syncthreads();

    f32x4 acc[2][8];
#pragma unroll
    for (int mi = 0; mi < 2; ++mi)
#pragma unroll
        for (int ni = 0; ni < 8; ++ni) acc[mi][ni] = (f32x4)0.f;

    const int arow0 = wr * 32 + (l & 15);
    const int kb    = (l >> 4) << 4;

#pragma unroll
    for (int ks = 0; ks < 6; ++ks) {
        bf16x8 a[2], b[8];
#pragma unroll
        for (int mi = 0; mi < 2; ++mi) {
            int row = arow0 + mi * 16;
            int off = (row * 384 + ks * 64 + kb) ^ ((row & 7) << 4);
            a[mi] = *(const bf16x8*)((const char*)As + off);
        }
#pragma unroll
        for (int ni = 0; ni < 8; ++ni) {
            int n = wc * 128 + ni * 16 + (l & 15);
            b[ni] = *(const bf16x8*)(WaT + (size_t)n * DIMC + ks * 32 + ((l >> 4) << 3));
        }
#pragma unroll
        for (int mi = 0; mi < 2; ++mi)
#pragma unroll
            for (int ni = 0; ni < 8; ++ni)
                acc[mi][ni] = __builtin_amdgcn_mfma_f32_16x16x32_bf16(
                    a[mi], b[ni], acc[mi][ni], 0, 0, 0);
    }

#pragma unroll
    for (int r0 = 0; r0 < 64; r0 += 16) {
        const int mi = (r0 >> 4) & 1;
        if (wr == (r0 >> 5)) {
#pragma unroll
            for (int ni = 0; ni < 8; ++ni) {
                int col = wc * 128 + ni * 16 + (l & 15);
                if (col < NATT) {
#pragma unroll
                    for (int r = 0; r < 4; ++r)
                        Cs[((l >> 4) << 2) + r][col] =
                            (mi == 0 ? acc[0][ni][r] : acc[1][ni][r]) + ba_s[col];
                }
            }
        }
        __syncthreads();
        for (int g = t; g < 864; g += 512) {
            int lr = g / 54;
            int cg = g - lr * 54;                 // head*9 + pp
            const float* ap = &Cs[lr][cg * 9];
            float mx = ap[0];
#pragma unroll
            for (int q = 1; q < 9; ++q) mx = fmaxf(mx, ap[q]);
            float e[9];
            float sum = 0.f;
#pragma unroll
            for (int q = 0; q < 9; ++q) { e[q] = __expf(ap[q] - mx); sum += e[q]; }
            float inv = 1.f / sum;
            int m = by * 64 + r0 + lr;
            unsigned short* dst = attn + ((size_t)m * 54 + cg) * 16;   // padded row
#pragma unroll
            for (int q = 0; q < 9; ++q) dst[q] = f2bf(e[q] * inv);
        }
        __syncthreads();
    }
}

// =====================================================================
// Gather (R5-proven structure): 25088 blocks, 2 same-parity pixels x
// 96 threads x 2 channels. Padded bf16 attn rows -> 2 loads per window.
// Bijective XCD swizzle: 2 whole batches per XCD, vp stays L2-hot.
// =====================================================================
template<int NI, int NJ>
static __device__ __forceinline__ void gather_body(
    int b, int p, int qc, int head, int c,
    const unsigned short* __restrict__ attn, const unsigned short* __restrict__ vp,
    unsigned short* __restrict__ y)
{
    const int pr = p >> 1;
    const int qr = qc >> 1;

    float accx = 0.f, accy = 0.f;

#pragma unroll
    for (int wi = 0; wi < NI; ++wi) {
        const bool hv  = (NI == 1) || (wi == 0) || (pr + 1 < HPOOL);
        const int  hhs = hv ? (pr + wi) : (HPOOL - 1);
        const int  iof = (NI == 1) ? 1 : (wi ? 0 : 2);
#pragma unroll
        for (int wj = 0; wj < NJ; ++wj) {
            const bool wv  = (NJ == 1) || (wj == 0) || (qr + 1 < WPOOL);
            const int  wws = wv ? (qr + wj) : (WPOOL - 1);
            const bool ok  = hv && wv;
            const int  jof = (NJ == 1) ? 1 : (wj ? 0 : 2);

            // padded attn row: 16 bf16, 32B aligned -> 1x bf16x8 + 1 ushort
            const unsigned short* ap = attn +
                ((size_t)((b * NPIX + hhs * WPOOL + wws) * 54 + head * 9 + iof * 3 + jof)) * 16;
            bf16x8 aw = *(const bf16x8*)ap;
            float a_[9];
#pragma unroll
            for (int k = 0; k < 8; ++k)
                a_[k] = ok ? bf2f((unsigned short)aw[k]) : 0.f;
            a_[8] = ok ? bf2f(ap[8]) : 0.f;

            const unsigned short* vb = vp +
                (((size_t)(b * VH + 2 * hhs)) * VW + 2 * wws) * DIMC + c;
            ushort2 v[9];
#pragma unroll
            for (int qi = 0; qi < 3; ++qi)
#pragma unroll
                for (int qj = 0; qj < 3; ++qj)
                    v[qi * 3 + qj] = *(const ushort2*)(vb + ((size_t)qi * VW + qj) * DIMC);

#pragma unroll
            for (int k = 0; k < 9; ++k) {
                accx = fmaf(a_[k], bf2f(v[k].x), accx);
                accy = fmaf(a_[k], bf2f(v[k].y), accy);
            }
        }
    }
    size_t pix = (size_t)b * (NH * NWW) + (size_t)p * NWW + qc;
    ushort2 r;
    r.x = f2bf(accx);
    r.y = f2bf(accy);
    *(ushort2*)(y + pix * DIMC + c) = r;
}

__global__ __launch_bounds__(192)
void gather_kernel(const unsigned short* __restrict__ attn,
                   const unsigned short* __restrict__ vp,
                   unsigned short* __restrict__ y)
{
    const int t    = threadIdx.x;
    const int pl   = t / 96;
    const int c2   = t - pl * 96;
    const int c    = c2 * 2;
    const int head = c2 >> 4;

    // bijective XCD swizzle: 25088 = 8*3136; XCD i owns batches 2i,2i+1,
    // swept (p, wq) row-major -> per-XCD working set ~2.6 MB stays L2-hot
    const int flat = blockIdx.x;
    const int wgid = (flat & 7) * 3136 + (flat >> 3);
    const int b    = wgid / 1568;
    const int rr   = wgid - b * 1568;
    const int p    = rr / 28;
    const int wq   = rr - p * 28;
    const int qc   = wq + pl * 28;          // pixel 0: wq, pixel 1: wq+28 (same parity)

    if (p & 1) {
        if (wq & 1) gather_body<2, 2>(b, p, qc, head, c, attn, vp, y);
        else        gather_body<2, 1>(b, p, qc, head, c, attn, vp, y);
    } else {
        if (wq & 1) gather_body<1, 2>(b, p, qc, head, c, attn, vp, y);
        else        gather_body<1, 1>(b, p, qc, head, c, attn, vp, y);
    }
}

// =====================================================================
extern "C" void kernel_launch(void* const* d_in, const int* in_sizes, int n_in,
                              void* d_out, int out_size, void* d_ws, size_t ws_size,
                              hipStream_t stream)
{
    const float* x  = (const float*)d_in[0];
    const float* Wv = (const float*)d_in[1];
    const float* Wa = (const float*)d_in[2];
    const float* ba = (const float*)d_in[3];
    const float* Wp = (const float*)d_in[4];
    const float* bp = (const float*)d_in[5];
    float* out = (float*)d_out;

    const size_t vp_elems   = (size_t)NB * VH * VW * DIMC;   // bf16
    const size_t attn_elems = (size_t)MPOOL * 54 * 16;       // bf16, padded rows
    const size_t y_elems    = (size_t)MROWS * DIMC;          // bf16

    unsigned short* vp   = (unsigned short*)d_ws;
    unsigned short* attn = vp + vp_elems;
    unsigned short* y    = attn + attn_elems;
    unsigned short* WTv  = y + y_elems;
    unsigned short* WTp  = WTv + 36864;
    unsigned short* WaT  = WTp + 36864;

    vp_border_zero_kernel<<<1369, 256, 0, stream>>>((unsigned int*)vp);
    wt_convert_kernel<<<672, 256, 0, stream>>>(Wv, Wp, Wa, WTv, WTp, WaT);

    mfma_gemm_kernel<0><<<MROWS / 64, 256, 0, stream>>>(x, WTv, nullptr, vp);
    pool_attn_mfma_kernel<<<MPOOL / 64, 512, 0, stream>>>(x, WaT, ba, attn);

    gather_kernel<<<25088, 192, 0, stream>>>(attn, vp, y);

    mfma_gemm_kernel<1><<<MROWS / 64, 256, 0, stream>>>(y, WTp, bp, out);
}

// Round 10
// 117.178 us; speedup vs baseline: 1.3707x; 1.0470x over previous
//
#include <hip/hip_runtime.h>
#include <cstdint>
#include <cstddef>

#define DIMC    192
#define NHEADS  6
#define NATT    486
#define NB      16
#define NH      56
#define NWW     56
#define HPOOL   28
#define WPOOL   28
#define NPIX    784
#define VH      58
#define VW      58
#define MROWS   (NB*NH*NWW)      // 50176
#define MPOOL   (NB*NPIX)        // 12544
#define SCALE_A 0.17677669529663687f

using bf16x8 = __attribute__((ext_vector_type(8))) short;
using f32x4  = __attribute__((ext_vector_type(4))) float;

static __device__ __forceinline__ unsigned short f2bf(float f) {
    unsigned int u = __float_as_uint(f);
    unsigned int r = (u + 0x7fffu + ((u >> 16) & 1u)) >> 16;   // RNE
    return (unsigned short)r;
}
static __device__ __forceinline__ float bf2f(unsigned short u) {
    return __uint_as_float((unsigned int)u << 16);
}

// =====================================================================
// Prep (one dispatch): WTv/WTp[n][k]=bf16(W[k][n]); WaT[512][192]=bf16(Wa*SCALE);
// zero vp border. 2040 blocks x 256 = 522240 = 172032 + 350208 exactly.
// =====================================================================
__global__ __launch_bounds__(256)
void prep_kernel(const float* __restrict__ Wv, const float* __restrict__ Wp,
                 const float* __restrict__ Wa,
                 unsigned short* __restrict__ WTv, unsigned short* __restrict__ WTp,
                 unsigned short* __restrict__ WaT, unsigned int* __restrict__ vpu)
{
    int idx = blockIdx.x * 256 + threadIdx.x;
    if (idx < 73728) {
        int sel = idx / 36864;
        int r   = idx - sel * 36864;
        int n   = r / DIMC;
        int k   = r - n * DIMC;
        const float* W = sel ? Wp : Wv;
        unsigned short* WT = sel ? WTp : WTv;
        WT[r] = f2bf(W[k * DIMC + n]);
    } else if (idx < 172032) {
        int r = idx - 73728;
        int n = r / DIMC;
        int k = r - n * DIMC;
        WaT[r] = (n < NATT) ? f2bf(Wa[(size_t)k * NATT + n] * SCALE_A) : (unsigned short)0;
    } else {
        int i2   = idx - 172032;                  // 0..350207
        int cu   = i2 % 96;
        int rest = i2 / 96;
        int b    = rest / 228;
        int p    = rest - b * 228;
        int hi, wi;
        if (p < 58)       { hi = 0;  wi = p; }
        else if (p < 116) { hi = 57; wi = p - 58; }
        else { int q = p - 116; hi = 1 + (q >> 1); wi = (q & 1) * 57; }
        vpu[(((size_t)b * VH + hi) * VW + wi) * 96 + cu] = 0u;
    }
}

// =====================================================================
// MFMA GEMM, BM=128, BN=192 (full N), 512 thr = 8 waves (4 row x 2 col).
// MODE 0: A fp32 (x), C bf16 -> padded vp   (LDS-staged coalesced stores)
// MODE 1: A bf16 (y), C fp32 + bias -> out  (LDS-staged coalesced stores)
// LDS 48KB -> 2 blocks/CU (16 waves), same residency as BM=64 x 4 blocks
// but half the barriers / B re-reads / per-block setup.
// =====================================================================
template<int MODE>
__global__ __launch_bounds__(512)
void gemm128_kernel(const void* __restrict__ Av, const unsigned short* __restrict__ WT,
                    const float* __restrict__ bias, void* __restrict__ Cv)
{
    __shared__ unsigned short As[128 * DIMC];   // 48 KB swizzled bf16 (reused in epilogue)

    const int t  = threadIdx.x;
    const int l  = t & 63;
    const int w  = t >> 6;
    const int wr = w >> 1;          // 0..3 : 32-row band
    const int wc = w & 1;           // 0..1 : 96-col half
    const int by = blockIdx.x;      // 0..391

    if (MODE == 0) {
        const float* Ab = (const float*)Av + (size_t)by * 128 * DIMC;
#pragma unroll
        for (int i = 0; i < 12; ++i) {
            int f = i * 2048 + t * 4;
            float4 v = *(const float4*)(Ab + f);
            int row = f / DIMC;
            int k   = f - row * DIMC;
            ushort4 u;
            u.x = f2bf(v.x); u.y = f2bf(v.y); u.z = f2bf(v.z); u.w = f2bf(v.w);
            int off = (row * 384 + k * 2) ^ ((row & 7) << 4);
            *(ushort4*)((char*)As + off) = u;
        }
    } else {
        const unsigned short* Ab = (const unsigned short*)Av + (size_t)by * 128 * DIMC;
#pragma unroll
        for (int i = 0; i < 6; ++i) {
            int f = i * 4096 + t * 8;
            bf16x8 v = *(const bf16x8*)(Ab + f);
            int row = f / DIMC;
            int k   = f - row * DIMC;
            int off = (row * 384 + k * 2) ^ ((row & 7) << 4);
            *(bf16x8*)((char*)As + off) = v;
        }
    }
    __syncthreads();

    f32x4 acc[2][6];
#pragma unroll
    for (int mi = 0; mi < 2; ++mi)
#pragma unroll
        for (int ni = 0; ni < 6; ++ni) acc[mi][ni] = (f32x4)0.f;

    const int arow0 = wr * 32 + (l & 15);
    const int kb    = (l >> 4) << 4;

#pragma unroll
    for (int ks = 0; ks < 6; ++ks) {
        bf16x8 a[2], b[6];
#pragma unroll
        for (int mi = 0; mi < 2; ++mi) {
            int row = arow0 + mi * 16;
            int off = (row * 384 + ks * 64 + kb) ^ ((row & 7) << 4);
            a[mi] = *(const bf16x8*)((const char*)As + off);
        }
#pragma unroll
        for (int ni = 0; ni < 6; ++ni) {
            int n = wc * 96 + ni * 16 + (l & 15);
            b[ni] = *(const bf16x8*)(WT + (size_t)n * DIMC + ks * 32 + ((l >> 4) << 3));
        }
#pragma unroll
        for (int mi = 0; mi < 2; ++mi)
#pragma unroll
            for (int ni = 0; ni < 6; ++ni)
                acc[mi][ni] = __builtin_amdgcn_mfma_f32_16x16x32_bf16(
                    a[mi], b[ni], acc[mi][ni], 0, 0, 0);
    }

    if (MODE == 0) {
        // stage bf16 C tile (128x192 = 48KB) in LDS, then coalesced 16B stores
        __syncthreads();
#pragma unroll
        for (int mi = 0; mi < 2; ++mi) {
#pragma unroll
            for (int r = 0; r < 4; ++r) {
                int row = wr * 32 + mi * 16 + ((l >> 4) << 2) + r;
#pragma unroll
                for (int ni = 0; ni < 6; ++ni) {
                    int col = wc * 96 + ni * 16 + (l & 15);
                    As[row * DIMC + col] = f2bf(acc[mi][ni][r]);
                }
            }
        }
        __syncthreads();
#pragma unroll
        for (int i = 0; i < 6; ++i) {
            int f   = i * 4096 + t * 8;       // ushort idx
            int row = f / DIMC;
            int k   = f - row * DIMC;
            int m   = by * 128 + row;
            int bb  = m / (NH * NWW);
            int rr  = m - bb * (NH * NWW);
            int hi  = rr / NWW;
            int wi  = rr - hi * NWW;
            bf16x8 v = *(const bf16x8*)&As[f];
            unsigned short* dst = (unsigned short*)Cv +
                (((size_t)bb * VH + hi + 1) * VW + (wi + 1)) * DIMC + k;
            *(bf16x8*)dst = v;
        }
    } else {
        // stage fp32 C in 4 chunks of 32 rows (24KB), coalesced float4 stores
        float* fAs = (float*)As;
#pragma unroll
        for (int chunk = 0; chunk < 4; ++chunk) {
            __syncthreads();
            if (wr == chunk) {
#pragma unroll
                for (int mi = 0; mi < 2; ++mi) {
#pragma unroll
                    for (int r = 0; r < 4; ++r) {
                        int rowl = mi * 16 + ((l >> 4) << 2) + r;
#pragma unroll
                        for (int ni = 0; ni < 6; ++ni) {
                            int col = wc * 96 + ni * 16 + (l & 15);
                            fAs[rowl * DIMC + col] = acc[mi][ni][r];
                        }
                    }
                }
            }
            __syncthreads();
#pragma unroll
            for (int i = 0; i < 3; ++i) {
                int f   = i * 2048 + t * 4;   // float idx, 6144 floats
                int row = f / DIMC;
                int k   = f - row * DIMC;
                int m   = by * 128 + chunk * 32 + row;
                float4 v  = *(const float4*)&fAs[f];
                float4 bv = *(const float4*)&bias[k];
                v.x += bv.x; v.y += bv.y; v.z += bv.z; v.w += bv.w;
                *(float4*)((float*)Cv + (size_t)m * DIMC + k) = v;
            }
        }
    }
}

// =====================================================================
// Fused pool + MFMA GEMM (M=12544, N=512pad, K=192) + softmax
// -> attn_pad bf16, layout [m][54][16] (9 weights + 7 pad per row)
// =====================================================================
__global__ __launch_bounds__(512)
void pool_attn_mfma_kernel(const float* __restrict__ x, const unsigned short* __restrict__ WaT,
                           const float* __restrict__ ba, unsigned short* __restrict__ attn)
{
    __shared__ unsigned short As[64 * DIMC];   // 24 KB
    __shared__ float Cs[16][489];              // 31.3 KB chunk
    __shared__ float ba_s[NATT];

    const int t  = threadIdx.x;
    const int l  = t & 63;
    const int w  = t >> 6;
    const int wr = w >> 2;
    const int wc = w & 3;
    const int by = blockIdx.x;

    if (t < NATT) ba_s[t] = ba[t] * SCALE_A;

#pragma unroll
    for (int i = 0; i < 6; ++i) {
        int f   = i * 2048 + t * 4;
        int row = f / DIMC;
        int k   = f - row * DIMC;
        int m   = by * 64 + row;
        int b   = m / NPIX;
        int r   = m - b * NPIX;
        int hh  = r / WPOOL;
        int ww  = r - hh * WPOOL;
        const float* xp = x + (((size_t)(b * NH + hh * 2)) * NWW + ww * 2) * DIMC + k;
        float4 v0 = *(const float4*)(xp);
        float4 v1 = *(const float4*)(xp + DIMC);
        float4 v2 = *(const float4*)(xp + (size_t)NWW * DIMC);
        float4 v3 = *(const float4*)(xp + (size_t)NWW * DIMC + DIMC);
        ushort4 u;
        u.x = f2bf(0.25f * (v0.x + v1.x + v2.x + v3.x));
        u.y = f2bf(0.25f * (v0.y + v1.y + v2.y + v3.y));
        u.z = f2bf(0.25f * (v0.z + v1.z + v2.z + v3.z));
        u.w = f2bf(0.25f * (v0.w + v1.w + v2.w + v3.w));
        int off = (row * 384 + k * 2) ^ ((row & 7) << 4);
        *(ushort4*)((char*)As + off) = u;
    }
    __syncthreads();

    f32x4 acc[2][8];
#pragma unroll
    for (int mi = 0; mi < 2; ++mi)
#pragma unroll
        for (int ni = 0; ni < 8; ++ni) acc[mi][ni] = (f32x4)0.f;

    const int arow0 = wr * 32 + (l & 15);
    const int kb    = (l >> 4) << 4;

#pragma unroll
    for (int ks = 0; ks < 6; ++ks) {
        bf16x8 a[2], b[8];
#pragma unroll
        for (int mi = 0; mi < 2; ++mi) {
            int row = arow0 + mi * 16;
            int off = (row * 384 + ks * 64 + kb) ^ ((row & 7) << 4);
            a[mi] = *(const bf16x8*)((const char*)As + off);
        }
#pragma unroll
        for (int ni = 0; ni < 8; ++ni) {
            int n = wc * 128 + ni * 16 + (l & 15);
            b[ni] = *(const bf16x8*)(WaT + (size_t)n * DIMC + ks * 32 + ((l >> 4) << 3));
        }
#pragma unroll
        for (int mi = 0; mi < 2; ++mi)
#pragma unroll
            for (int ni = 0; ni < 8; ++ni)
                acc[mi][ni] = __builtin_amdgcn_mfma_f32_16x16x32_bf16(
                    a[mi], b[ni], acc[mi][ni], 0, 0, 0);
    }

#pragma unroll
    for (int r0 = 0; r0 < 64; r0 += 16) {
        const int mi = (r0 >> 4) & 1;
        if (wr == (r0 >> 5)) {
#pragma unroll
            for (int ni = 0; ni < 8; ++ni) {
                int col = wc * 128 + ni * 16 + (l & 15);
                if (col < NATT) {
#pragma unroll
                    for (int r = 0; r < 4; ++r)
                        Cs[((l >> 4) << 2) + r][col] =
                            (mi == 0 ? acc[0][ni][r] : acc[1][ni][r]) + ba_s[col];
                }
            }
        }
        __syncthreads();
        for (int g = t; g < 864; g += 512) {
            int lr = g / 54;
            int cg = g - lr * 54;                 // head*9 + pp
            const float* ap = &Cs[lr][cg * 9];
            float mx = ap[0];
#pragma unroll
            for (int q = 1; q < 9; ++q) mx = fmaxf(mx, ap[q]);
            float e[9];
            float sum = 0.f;
#pragma unroll
            for (int q = 0; q < 9; ++q) { e[q] = __expf(ap[q] - mx); sum += e[q]; }
            float inv = 1.f / sum;
            int m = by * 64 + r0 + lr;
            unsigned short* dst = attn + ((size_t)m * 54 + cg) * 16;   // padded row
#pragma unroll
            for (int q = 0; q < 9; ++q) dst[q] = f2bf(e[q] * inv);
        }
        __syncthreads();
    }
}

// =====================================================================
// Gather (proven R9 form): 25088 blocks, 2 same-parity pixels x 96 thr
// x 2 ch. Padded bf16 attn rows -> 2 loads per window. XCD batch sweep.
// =====================================================================
template<int NI, int NJ>
static __device__ __forceinline__ void gather_body(
    int b, int p, int qc, int head, int c,
    const unsigned short* __restrict__ attn, const unsigned short* __restrict__ vp,
    unsigned short* __restrict__ y)
{
    const int pr = p >> 1;
    const int qr = qc >> 1;

    float accx = 0.f, accy = 0.f;

#pragma unroll
    for (int wi = 0; wi < NI; ++wi) {
        const bool hv  = (NI == 1) || (wi == 0) || (pr + 1 < HPOOL);
        const int  hhs = hv ? (pr + wi) : (HPOOL - 1);
        const int  iof = (NI == 1) ? 1 : (wi ? 0 : 2);
#pragma unroll
        for (int wj = 0; wj < NJ; ++wj) {
            const bool wv  = (NJ == 1) || (wj == 0) || (qr + 1 < WPOOL);
            const int  wws = wv ? (qr + wj) : (WPOOL - 1);
            const bool ok  = hv && wv;
            const int  jof = (NJ == 1) ? 1 : (wj ? 0 : 2);

            const unsigned short* ap = attn +
                ((size_t)((b * NPIX + hhs * WPOOL + wws) * 54 + head * 9 + iof * 3 + jof)) * 16;
            bf16x8 aw = *(const bf16x8*)ap;
            float a_[9];
#pragma unroll
            for (int k = 0; k < 8; ++k)
                a_[k] = ok ? bf2f((unsigned short)aw[k]) : 0.f;
            a_[8] = ok ? bf2f(ap[8]) : 0.f;

            const unsigned short* vb = vp +
                (((size_t)(b * VH + 2 * hhs)) * VW + 2 * wws) * DIMC + c;
            ushort2 v[9];
#pragma unroll
            for (int qi = 0; qi < 3; ++qi)
#pragma unroll
                for (int qj = 0; qj < 3; ++qj)
                    v[qi * 3 + qj] = *(const ushort2*)(vb + ((size_t)qi * VW + qj) * DIMC);

#pragma unroll
            for (int k = 0; k < 9; ++k) {
                accx = fmaf(a_[k], bf2f(v[k].x), accx);
                accy = fmaf(a_[k], bf2f(v[k].y), accy);
            }
        }
    }
    size_t pix = (size_t)b * (NH * NWW) + (size_t)p * NWW + qc;
    ushort2 r;
    r.x = f2bf(accx);
    r.y = f2bf(accy);
    *(ushort2*)(y + pix * DIMC + c) = r;
}

__global__ __launch_bounds__(192)
void gather_kernel(const unsigned short* __restrict__ attn,
                   const unsigned short* __restrict__ vp,
                   unsigned short* __restrict__ y)
{
    const int t    = threadIdx.x;
    const int pl   = t / 96;
    const int c2   = t - pl * 96;
    const int c    = c2 * 2;
    const int head = c2 >> 4;

    const int flat = blockIdx.x;
    const int wgid = (flat & 7) * 3136 + (flat >> 3);
    const int b    = wgid / 1568;
    const int rr   = wgid - b * 1568;
    const int p    = rr / 28;
    const int wq   = rr - p * 28;
    const int qc   = wq + pl * 28;

    if (p & 1) {
        if (wq & 1) gather_body<2, 2>(b, p, qc, head, c, attn, vp, y);
        else        gather_body<2, 1>(b, p, qc, head, c, attn, vp, y);
    } else {
        if (wq & 1) gather_body<1, 2>(b, p, qc, head, c, attn, vp, y);
        else        gather_body<1, 1>(b, p, qc, head, c, attn, vp, y);
    }
}

// =====================================================================
extern "C" void kernel_launch(void* const* d_in, const int* in_sizes, int n_in,
                              void* d_out, int out_size, void* d_ws, size_t ws_size,
                              hipStream_t stream)
{
    const float* x  = (const float*)d_in[0];
    const float* Wv = (const float*)d_in[1];
    const float* Wa = (const float*)d_in[2];
    const float* ba = (const float*)d_in[3];
    const float* Wp = (const float*)d_in[4];
    const float* bp = (const float*)d_in[5];
    float* out = (float*)d_out;

    const size_t vp_elems   = (size_t)NB * VH * VW * DIMC;   // bf16
    const size_t attn_elems = (size_t)MPOOL * 54 * 16;       // bf16, padded rows
    const size_t y_elems    = (size_t)MROWS * DIMC;          // bf16

    unsigned short* vp   = (unsigned short*)d_ws;
    unsigned short* attn = vp + vp_elems;
    unsigned short* y    = attn + attn_elems;
    unsigned short* WTv  = y + y_elems;
    unsigned short* WTp  = WTv + 36864;
    unsigned short* WaT  = WTp + 36864;

    prep_kernel<<<2040, 256, 0, stream>>>(Wv, Wp, Wa, WTv, WTp, WaT, (unsigned int*)vp);

    gemm128_kernel<0><<<MROWS / 128, 512, 0, stream>>>(x, WTv, nullptr, vp);
    pool_attn_mfma_kernel<<<MPOOL / 64, 512, 0, stream>>>(x, WaT, ba, attn);

    gather_kernel<<<25088, 192, 0, stream>>>(attn, vp, y);

    gemm128_kernel<1><<<MROWS / 128, 512, 0, stream>>>(y, WTp, bp, out);
}

// Round 11
// 114.001 us; speedup vs baseline: 1.4089x; 1.0279x over previous
//
#include <hip/hip_runtime.h>
#include <cstdint>
#include <cstddef>

#define DIMC    192
#define NHEADS  6
#define NATT    486
#define NB      16
#define NH      56
#define NWW     56
#define HPOOL   28
#define WPOOL   28
#define NPIX    784
#define VH      58
#define VW      58
#define MROWS   (NB*NH*NWW)      // 50176
#define MPOOL   (NB*NPIX)        // 12544
#define SCALE_A 0.17677669529663687f

using bf16x8 = __attribute__((ext_vector_type(8))) short;
using f32x4  = __attribute__((ext_vector_type(4))) float;

static __device__ __forceinline__ unsigned short f2bf(float f) {
    unsigned int u = __float_as_uint(f);
    unsigned int r = (u + 0x7fffu + ((u >> 16) & 1u)) >> 16;   // RNE
    return (unsigned short)r;
}
static __device__ __forceinline__ float bf2f(unsigned short u) {
    return __uint_as_float((unsigned int)u << 16);
}

// =====================================================================
// Prep: WTv/WTp[n][k]=bf16(W[k][n]); WaT[512][192]=bf16(Wa*SCALE); vp border=0
// =====================================================================
__global__ __launch_bounds__(256)
void prep_kernel(const float* __restrict__ Wv, const float* __restrict__ Wp,
                 const float* __restrict__ Wa,
                 unsigned short* __restrict__ WTv, unsigned short* __restrict__ WTp,
                 unsigned short* __restrict__ WaT, unsigned int* __restrict__ vpu)
{
    int idx = blockIdx.x * 256 + threadIdx.x;
    if (idx < 73728) {
        int sel = idx / 36864;
        int r   = idx - sel * 36864;
        int n   = r / DIMC;
        int k   = r - n * DIMC;
        const float* W = sel ? Wp : Wv;
        unsigned short* WT = sel ? WTp : WTv;
        WT[r] = f2bf(W[k * DIMC + n]);
    } else if (idx < 172032) {
        int r = idx - 73728;
        int n = r / DIMC;
        int k = r - n * DIMC;
        WaT[r] = (n < NATT) ? f2bf(Wa[(size_t)k * NATT + n] * SCALE_A) : (unsigned short)0;
    } else {
        int i2   = idx - 172032;                  // 0..350207
        int cu   = i2 % 96;
        int rest = i2 / 96;
        int b    = rest / 228;
        int p    = rest - b * 228;
        int hi, wi;
        if (p < 58)       { hi = 0;  wi = p; }
        else if (p < 116) { hi = 57; wi = p - 58; }
        else { int q = p - 116; hi = 1 + (q >> 1); wi = (q & 1) * 57; }
        vpu[(((size_t)b * VH + hi) * VW + wi) * 96 + cu] = 0u;
    }
}

// =====================================================================
// GEMM0 body (BM=128, 8 waves): x fp32 @ WTv -> bf16 padded vp
// =====================================================================
static __device__ __forceinline__
void gemm0_body(const float* __restrict__ x, const unsigned short* __restrict__ WT,
                unsigned short* __restrict__ vp, int by, int t, char* smem)
{
    unsigned short* As = (unsigned short*)smem;   // 48 KB swizzled bf16

    const int l  = t & 63;
    const int w  = t >> 6;
    const int wr = w >> 1;
    const int wc = w & 1;

    const float* Ab = x + (size_t)by * 128 * DIMC;
#pragma unroll
    for (int i = 0; i < 12; ++i) {
        int f = i * 2048 + t * 4;
        float4 v = *(const float4*)(Ab + f);
        int row = f / DIMC;
        int k   = f - row * DIMC;
        ushort4 u;
        u.x = f2bf(v.x); u.y = f2bf(v.y); u.z = f2bf(v.z); u.w = f2bf(v.w);
        int off = (row * 384 + k * 2) ^ ((row & 7) << 4);
        *(ushort4*)((char*)As + off) = u;
    }
    __syncthreads();

    f32x4 acc[2][6];
#pragma unroll
    for (int mi = 0; mi < 2; ++mi)
#pragma unroll
        for (int ni = 0; ni < 6; ++ni) acc[mi][ni] = (f32x4)0.f;

    const int arow0 = wr * 32 + (l & 15);
    const int kb    = (l >> 4) << 4;

#pragma unroll
    for (int ks = 0; ks < 6; ++ks) {
        bf16x8 a[2], b[6];
#pragma unroll
        for (int mi = 0; mi < 2; ++mi) {
            int row = arow0 + mi * 16;
            int off = (row * 384 + ks * 64 + kb) ^ ((row & 7) << 4);
            a[mi] = *(const bf16x8*)((const char*)As + off);
        }
#pragma unroll
        for (int ni = 0; ni < 6; ++ni) {
            int n = wc * 96 + ni * 16 + (l & 15);
            b[ni] = *(const bf16x8*)(WT + (size_t)n * DIMC + ks * 32 + ((l >> 4) << 3));
        }
#pragma unroll
        for (int mi = 0; mi < 2; ++mi)
#pragma unroll
            for (int ni = 0; ni < 6; ++ni)
                acc[mi][ni] = __builtin_amdgcn_mfma_f32_16x16x32_bf16(
                    a[mi], b[ni], acc[mi][ni], 0, 0, 0);
    }

    // epilogue: stage bf16 tile in LDS, coalesced 16B stores into padded vp
    __syncthreads();
#pragma unroll
    for (int mi = 0; mi < 2; ++mi) {
#pragma unroll
        for (int r = 0; r < 4; ++r) {
            int row = wr * 32 + mi * 16 + ((l >> 4) << 2) + r;
#pragma unroll
            for (int ni = 0; ni < 6; ++ni) {
                int col = wc * 96 + ni * 16 + (l & 15);
                As[row * DIMC + col] = f2bf(acc[mi][ni][r]);
            }
        }
    }
    __syncthreads();
#pragma unroll
    for (int i = 0; i < 6; ++i) {
        int f   = i * 4096 + t * 8;
        int row = f / DIMC;
        int k   = f - row * DIMC;
        int m   = by * 128 + row;
        int bb  = m / (NH * NWW);
        int rr  = m - bb * (NH * NWW);
        int hi  = rr / NWW;
        int wi  = rr - hi * NWW;
        bf16x8 v = *(const bf16x8*)&As[f];
        unsigned short* dst = vp + (((size_t)bb * VH + hi + 1) * VW + (wi + 1)) * DIMC + k;
        *(bf16x8*)dst = v;
    }
}

// =====================================================================
// pool+attn body (BM=64, 8 waves 2x4): pooled @ WaT + softmax -> attn_pad
// =====================================================================
static __device__ __forceinline__
void pool_body(const float* __restrict__ x, const unsigned short* __restrict__ WaT,
               const float* __restrict__ ba, unsigned short* __restrict__ attn,
               int by, int t, char* smem)
{
    unsigned short* As = (unsigned short*)smem;                 // 24 KB
    float (*Cs)[489]   = (float(*)[489])(smem + 24576);         // 31.3 KB
    float* ba_s        = (float*)(smem + 24576 + 31296);        // 1.9 KB

    const int l  = t & 63;
    const int w  = t >> 6;
    const int wr = w >> 2;
    const int wc = w & 3;

    if (t < NATT) ba_s[t] = ba[t] * SCALE_A;

#pragma unroll
    for (int i = 0; i < 6; ++i) {
        int f   = i * 2048 + t * 4;
        int row = f / DIMC;
        int k   = f - row * DIMC;
        int m   = by * 64 + row;
        int b   = m / NPIX;
        int r   = m - b * NPIX;
        int hh  = r / WPOOL;
        int ww  = r - hh * WPOOL;
        const float* xp = x + (((size_t)(b * NH + hh * 2)) * NWW + ww * 2) * DIMC + k;
        float4 v0 = *(const float4*)(xp);
        float4 v1 = *(const float4*)(xp + DIMC);
        float4 v2 = *(const float4*)(xp + (size_t)NWW * DIMC);
        float4 v3 = *(const float4*)(xp + (size_t)NWW * DIMC + DIMC);
        ushort4 u;
        u.x = f2bf(0.25f * (v0.x + v1.x + v2.x + v3.x));
        u.y = f2bf(0.25f * (v0.y + v1.y + v2.y + v3.y));
        u.z = f2bf(0.25f * (v0.z + v1.z + v2.z + v3.z));
        u.w = f2bf(0.25f * (v0.w + v1.w + v2.w + v3.w));
        int off = (row * 384 + k * 2) ^ ((row & 7) << 4);
        *(ushort4*)((char*)As + off) = u;
    }
    __syncthreads();

    f32x4 acc[2][8];
#pragma unroll
    for (int mi = 0; mi < 2; ++mi)
#pragma unroll
        for (int ni = 0; ni < 8; ++ni) acc[mi][ni] = (f32x4)0.f;

    const int arow0 = wr * 32 + (l & 15);
    const int kb    = (l >> 4) << 4;

#pragma unroll
    for (int ks = 0; ks < 6; ++ks) {
        bf16x8 a[2], b[8];
#pragma unroll
        for (int mi = 0; mi < 2; ++mi) {
            int row = arow0 + mi * 16;
            int off = (row * 384 + ks * 64 + kb) ^ ((row & 7) << 4);
            a[mi] = *(const bf16x8*)((const char*)As + off);
        }
#pragma unroll
        for (int ni = 0; ni < 8; ++ni) {
            int n = wc * 128 + ni * 16 + (l & 15);
            b[ni] = *(const bf16x8*)(WaT + (size_t)n * DIMC + ks * 32 + ((l >> 4) << 3));
        }
#pragma unroll
        for (int mi = 0; mi < 2; ++mi)
#pragma unroll
            for (int ni = 0; ni < 8; ++ni)
                acc[mi][ni] = __builtin_amdgcn_mfma_f32_16x16x32_bf16(
                    a[mi], b[ni], acc[mi][ni], 0, 0, 0);
    }

#pragma unroll
    for (int r0 = 0; r0 < 64; r0 += 16) {
        const int mi = (r0 >> 4) & 1;
        if (wr == (r0 >> 5)) {
#pragma unroll
            for (int ni = 0; ni < 8; ++ni) {
                int col = wc * 128 + ni * 16 + (l & 15);
                if (col < NATT) {
#pragma unroll
                    for (int r = 0; r < 4; ++r)
                        Cs[((l >> 4) << 2) + r][col] =
                            (mi == 0 ? acc[0][ni][r] : acc[1][ni][r]) + ba_s[col];
                }
            }
        }
        __syncthreads();
        for (int g = t; g < 864; g += 512) {
            int lr = g / 54;
            int cg = g - lr * 54;                 // head*9 + pp
            const float* ap = &Cs[lr][cg * 9];
            float mx = ap[0];
#pragma unroll
            for (int q = 1; q < 9; ++q) mx = fmaxf(mx, ap[q]);
            float e[9];
            float sum = 0.f;
#pragma unroll
            for (int q = 0; q < 9; ++q) { e[q] = __expf(ap[q] - mx); sum += e[q]; }
            float inv = 1.f / sum;
            int m = by * 64 + r0 + lr;
            unsigned short* dst = attn + ((size_t)m * 54 + cg) * 16;   // padded row
#pragma unroll
            for (int q = 0; q < 9; ++q) dst[q] = f2bf(e[q] * inv);
        }
        __syncthreads();
    }
}

// =====================================================================
// Phase 1 fused dispatch: blocks 0..391 = GEMM0, 392..587 = pool+attn
// =====================================================================
__global__ __launch_bounds__(512)
void phase1_kernel(const float* __restrict__ x, const unsigned short* __restrict__ WTv,
                   const unsigned short* __restrict__ WaT, const float* __restrict__ ba,
                   unsigned short* __restrict__ vp, unsigned short* __restrict__ attn)
{
    __shared__ __align__(16) char smem[57816];   // max(48K gemm, 57.8K pool)
    const int t = threadIdx.x;
    if (blockIdx.x < 392) gemm0_body(x, WTv, vp, blockIdx.x, t, smem);
    else                  pool_body(x, WaT, ba, attn, blockIdx.x - 392, t, smem);
}

// =====================================================================
// GEMM1 (BM=128, 8 waves): y bf16 @ WTp + bp -> out fp32
// =====================================================================
__global__ __launch_bounds__(512)
void gemm1_kernel(const unsigned short* __restrict__ Av, const unsigned short* __restrict__ WT,
                  const float* __restrict__ bias, float* __restrict__ Cv)
{
    __shared__ unsigned short As[128 * DIMC];   // 48 KB

    const int t  = threadIdx.x;
    const int l  = t & 63;
    const int w  = t >> 6;
    const int wr = w >> 1;
    const int wc = w & 1;
    const int by = blockIdx.x;

    const unsigned short* Ab = Av + (size_t)by * 128 * DIMC;
#pragma unroll
    for (int i = 0; i < 6; ++i) {
        int f = i * 4096 + t * 8;
        bf16x8 v = *(const bf16x8*)(Ab + f);
        int row = f / DIMC;
        int k   = f - row * DIMC;
        int off = (row * 384 + k * 2) ^ ((row & 7) << 4);
        *(bf16x8*)((char*)As + off) = v;
    }
    __syncthreads();

    f32x4 acc[2][6];
#pragma unroll
    for (int mi = 0; mi < 2; ++mi)
#pragma unroll
        for (int ni = 0; ni < 6; ++ni) acc[mi][ni] = (f32x4)0.f;

    const int arow0 = wr * 32 + (l & 15);
    const int kb    = (l >> 4) << 4;

#pragma unroll
    for (int ks = 0; ks < 6; ++ks) {
        bf16x8 a[2], b[6];
#pragma unroll
        for (int mi = 0; mi < 2; ++mi) {
            int row = arow0 + mi * 16;
            int off = (row * 384 + ks * 64 + kb) ^ ((row & 7) << 4);
            a[mi] = *(const bf16x8*)((const char*)As + off);
        }
#pragma unroll
        for (int ni = 0; ni < 6; ++ni) {
            int n = wc * 96 + ni * 16 + (l & 15);
            b[ni] = *(const bf16x8*)(WT + (size_t)n * DIMC + ks * 32 + ((l >> 4) << 3));
        }
#pragma unroll
        for (int mi = 0; mi < 2; ++mi)
#pragma unroll
            for (int ni = 0; ni < 6; ++ni)
                acc[mi][ni] = __builtin_amdgcn_mfma_f32_16x16x32_bf16(
                    a[mi], b[ni], acc[mi][ni], 0, 0, 0);
    }

    // epilogue: 4 chunks of 32 rows through LDS, coalesced float4 stores
    float* fAs = (float*)As;
#pragma unroll
    for (int chunk = 0; chunk < 4; ++chunk) {
        __syncthreads();
        if (wr == chunk) {
#pragma unroll
            for (int mi = 0; mi < 2; ++mi) {
#pragma unroll
                for (int r = 0; r < 4; ++r) {
                    int rowl = mi * 16 + ((l >> 4) << 2) + r;
#pragma unroll
                    for (int ni = 0; ni < 6; ++ni) {
                        int col = wc * 96 + ni * 16 + (l & 15);
                        fAs[rowl * DIMC + col] = acc[mi][ni][r];
                    }
                }
            }
        }
        __syncthreads();
#pragma unroll
        for (int i = 0; i < 3; ++i) {
            int f   = i * 2048 + t * 4;
            int row = f / DIMC;
            int k   = f - row * DIMC;
            int m   = by * 128 + chunk * 32 + row;
            float4 v  = *(const float4*)&fAs[f];
            float4 bv = *(const float4*)&bias[k];
            v.x += bv.x; v.y += bv.y; v.z += bv.z; v.w += bv.w;
            *(float4*)(Cv + (size_t)m * DIMC + k) = v;
        }
    }
}

// =====================================================================
// Gather (R9 structure + batched loads): 25088 blocks, 2 same-parity
// pixels x 96 thr x 2 ch. ALL loads issued before FMAs (deep MLP).
// =====================================================================
template<int NI, int NJ>
static __device__ __forceinline__ void gather_body(
    int b, int p, int qc, int head, int c,
    const unsigned short* __restrict__ attn, const unsigned short* __restrict__ vp,
    unsigned short* __restrict__ y)
{
    const int pr = p >> 1;
    const int qr = qc >> 1;

    bf16x8        aw8[NI * NJ];
    unsigned short aw9[NI * NJ];
    ushort2       v[NI * NJ][9];
    bool          ok[NI * NJ];

    // ---- phase 1: issue ALL loads ----
#pragma unroll
    for (int wi = 0; wi < NI; ++wi) {
        const bool hv  = (NI == 1) || (wi == 0) || (pr + 1 < HPOOL);
        const int  hhs = hv ? (pr + wi) : (HPOOL - 1);
        const int  iof = (NI == 1) ? 1 : (wi ? 0 : 2);
#pragma unroll
        for (int wj = 0; wj < NJ; ++wj) {
            const bool wv  = (NJ == 1) || (wj == 0) || (qr + 1 < WPOOL);
            const int  wws = wv ? (qr + wj) : (WPOOL - 1);
            const int  jof = (NJ == 1) ? 1 : (wj ? 0 : 2);
            const int  idx = wi * NJ + wj;
            ok[idx] = hv && wv;

            const unsigned short* ap = attn +
                ((size_t)((b * NPIX + hhs * WPOOL + wws) * 54 + head * 9 + iof * 3 + jof)) * 16;
            aw8[idx] = *(const bf16x8*)ap;
            aw9[idx] = ap[8];

            const unsigned short* vb = vp +
                (((size_t)(b * VH + 2 * hhs)) * VW + 2 * wws) * DIMC + c;
#pragma unroll
            for (int qi = 0; qi < 3; ++qi)
#pragma unroll
                for (int qj = 0; qj < 3; ++qj)
                    v[idx][qi * 3 + qj] = *(const ushort2*)(vb + ((size_t)qi * VW + qj) * DIMC);
        }
    }

    // ---- phase 2: FMA sweep ----
    float accx = 0.f, accy = 0.f;
#pragma unroll
    for (int idx = 0; idx < NI * NJ; ++idx) {
#pragma unroll
        for (int k = 0; k < 9; ++k) {
            float a = ok[idx]
                ? ((k < 8) ? bf2f((unsigned short)aw8[idx][k]) : bf2f(aw9[idx]))
                : 0.f;
            accx = fmaf(a, bf2f(v[idx][k].x), accx);
            accy = fmaf(a, bf2f(v[idx][k].y), accy);
        }
    }

    size_t pix = (size_t)b * (NH * NWW) + (size_t)p * NWW + qc;
    ushort2 r;
    r.x = f2bf(accx);
    r.y = f2bf(accy);
    *(ushort2*)(y + pix * DIMC + c) = r;
}

__global__ __launch_bounds__(192)
void gather_kernel(const unsigned short* __restrict__ attn,
                   const unsigned short* __restrict__ vp,
                   unsigned short* __restrict__ y)
{
    const int t    = threadIdx.x;
    const int pl   = t / 96;
    const int c2   = t - pl * 96;
    const int c    = c2 * 2;
    const int head = c2 >> 4;

    const int flat = blockIdx.x;
    const int wgid = (flat & 7) * 3136 + (flat >> 3);
    const int b    = wgid / 1568;
    const int rr   = wgid - b * 1568;
    const int p    = rr / 28;
    const int wq   = rr - p * 28;
    const int qc   = wq + pl * 28;

    if (p & 1) {
        if (wq & 1) gather_body<2, 2>(b, p, qc, head, c, attn, vp, y);
        else        gather_body<2, 1>(b, p, qc, head, c, attn, vp, y);
    } else {
        if (wq & 1) gather_body<1, 2>(b, p, qc, head, c, attn, vp, y);
        else        gather_body<1, 1>(b, p, qc, head, c, attn, vp, y);
    }
}

// =====================================================================
extern "C" void kernel_launch(void* const* d_in, const int* in_sizes, int n_in,
                              void* d_out, int out_size, void* d_ws, size_t ws_size,
                              hipStream_t stream)
{
    const float* x  = (const float*)d_in[0];
    const float* Wv = (const float*)d_in[1];
    const float* Wa = (const float*)d_in[2];
    const float* ba = (const float*)d_in[3];
    const float* Wp = (const float*)d_in[4];
    const float* bp = (const float*)d_in[5];
    float* out = (float*)d_out;

    const size_t vp_elems   = (size_t)NB * VH * VW * DIMC;   // bf16
    const size_t attn_elems = (size_t)MPOOL * 54 * 16;       // bf16, padded rows
    const size_t y_elems    = (size_t)MROWS * DIMC;          // bf16

    unsigned short* vp   = (unsigned short*)d_ws;
    unsigned short* attn = vp + vp_elems;
    unsigned short* y    = attn + attn_elems;
    unsigned short* WTv  = y + y_elems;
    unsigned short* WTp  = WTv + 36864;
    unsigned short* WaT  = WTp + 36864;

    prep_kernel<<<2040, 256, 0, stream>>>(Wv, Wp, Wa, WTv, WTp, WaT, (unsigned int*)vp);

    phase1_kernel<<<588, 512, 0, stream>>>(x, WTv, WaT, ba, vp, attn);

    gather_kernel<<<25088, 192, 0, stream>>>(attn, vp, y);

    gemm1_kernel<<<MROWS / 128, 512, 0, stream>>>(y, WTp, bp, out);
}